// Round 16
// baseline (139.156 us; speedup 1.0000x reference)
//
#include <hip/hip_runtime.h>
#include <stdint.h>

#define B_   8
#define N_   8192
#define S_   2048
#define D1_  128
#define D2_  256
#define CIN_ 384
#define C1_  256
#define C2_  128
#define NSUB_ 4

typedef uint16_t u16;
typedef uint32_t u32;
typedef __attribute__((ext_vector_type(8))) short bf16x8;
typedef __attribute__((ext_vector_type(4))) float f32x4;

static __device__ __forceinline__ u16 f2bf(float f){
    union { float f; u32 u; } v; v.f = f;
    u32 r = v.u + 0x7FFF + ((v.u >> 16) & 1);
    return (u16)(r >> 16);
}
static __device__ __forceinline__ float bf2f(u16 h){
    union { u32 u; float f; } v; v.u = ((u32)h) << 16;
    return v.f;
}
static __device__ __forceinline__ uint4 pack8(const u16 h[8]){
    uint4 u;
    u.x = (u32)h[0] | ((u32)h[1] << 16);
    u.y = (u32)h[2] | ((u32)h[3] << 16);
    u.z = (u32)h[4] | ((u32)h[5] << 16);
    u.w = (u32)h[6] | ((u32)h[7] << 16);
    return u;
}
#define EXT8(dst, u) { dst[0]=bf2f((u16)(u).x); dst[1]=bf2f((u16)((u).x>>16)); \
                       dst[2]=bf2f((u16)(u).y); dst[3]=bf2f((u16)((u).y>>16)); \
                       dst[4]=bf2f((u16)(u).z); dst[5]=bf2f((u16)((u).z>>16)); \
                       dst[6]=bf2f((u16)(u).w); dst[7]=bf2f((u16)((u).w>>16)); }

static __device__ __forceinline__ float med3f(float a, float b, float c){
    float d;
    asm("v_med3_f32 %0, %1, %2, %3" : "=v"(d) : "v"(a), "v"(b), "v"(c));
    return d;
}

// ---------------- fused pre-pass: k_nn (blocks 0..1023) + p2t (1024..5119) + prep_w (5120..5503) ----------------
#define INSV(sc) do{ \
    float t2_ = med3f(A1, A2, (sc)); \
    float t1_ = med3f(A0, A1, (sc)); \
    A0 = fmaxf(A0, (sc)); \
    A1 = t1_; A2 = t2_; \
}while(0)
#define INSVB(sc) do{ \
    float t2_ = med3f(Bb1, Bb2, (sc)); \
    float t1_ = med3f(Bb0, Bb1, (sc)); \
    Bb0 = fmaxf(Bb0, (sc)); \
    Bb1 = t1_; Bb2 = t2_; \
}while(0)
#define INSL(sc, si) do{ \
    bool c0 = ((sc) > L0) || ((sc) == L0 && (si) < K0); \
    bool c1 = ((sc) > L1) || ((sc) == L1 && (si) < K1); \
    bool c2 = ((sc) > L2) || ((sc) == L2 && (si) < K2); \
    int K2n = c2 ? (c1 ? K1 : (si)) : K2; \
    int K1n = c1 ? (c0 ? K0 : (si)) : K1; \
    int K0n = c0 ? (si) : K0; \
    float T2 = med3f(L1, L2, (sc)); \
    float T1 = med3f(L0, L1, (sc)); \
    L0 = fmaxf(L0, (sc)); \
    L1 = T1; L2 = T2; K0 = K0n; K1 = K1n; K2 = K2n; \
}while(0)

__global__ __launch_bounds__(256) void k_pre(const float* __restrict__ xyz1,
                                             const float* __restrict__ xyz2,
                                             const float* __restrict__ p2,
                                             const float* __restrict__ w1,
                                             const float* __restrict__ w2,
                                             int4* __restrict__ nn_idx4, float4* __restrict__ nn_w4,
                                             u16* __restrict__ p2t, u16* __restrict__ w1bf,
                                             u16* __restrict__ w2bf){
    __shared__ __attribute__((aligned(16))) char smem[4*513*16];
    int bid = blockIdx.x;
    int t = threadIdx.x;

    if (bid < 1024){
        // ================= k_nn v5 (byte-identical body) =================
        float4* pt = (float4*)smem;          // [4*513], quarter q at pt + q*513
        int b = bid >> 7;
        int bx = bid & 127;
        const float* xb = xyz2 + (size_t)b*3*S_;
        for (int i = t; i < S_; i += 256){
            float x = xb[i], y = xb[S_ + i], z = xb[2*S_ + i];
            float hw = 0.5f*(x*x + y*y + z*z);
            pt[(i >> 9)*513 + (i & 511)] = make_float4(x, y, z, hw);
        }
        __syncthreads();
        int nl = t >> 2, q = t & 3;
        int n = bx * 64 + nl;
        const float* x1b = xyz1 + (size_t)b*3*N_;
        float px = x1b[n], py = x1b[N_ + n], pz = x1b[2*N_ + n];
        float n1 = px*px + py*py + pz*pz;
        const float4* ptq = pt + q*513;
        const int sQ = q * 512;

        float A0 = -3.4e38f, A1 = -3.4e38f, A2 = -3.4e38f;
        float Bb0 = -3.4e38f, Bb1 = -3.4e38f, Bb2 = -3.4e38f;
        #pragma unroll 4
        for (int j = 0; j < 512; j += 2){
            float4 qa = ptq[j];
            float4 qb = ptq[j+1];
            float sa = fmaf(px, qa.x, fmaf(py, qa.y, fmaf(pz, qa.z, -qa.w)));
            float sb = fmaf(px, qb.x, fmaf(py, qb.y, fmaf(pz, qb.z, -qb.w)));
            INSV(sa);
            INSVB(sb);
        }
        INSV(Bb0); INSV(Bb1); INSV(Bb2);
        #pragma unroll
        for (int m = 1; m <= 2; m <<= 1){
            float e0=__shfl_xor(A0,m), e1=__shfl_xor(A1,m), e2=__shfl_xor(A2,m);
            INSV(e0); INSV(e1); INSV(e2);
        }
        const float M0 = A0, M1 = A1, M2 = A2;

        int i0 = 0x7FFFFFFF, i1 = 0x7FFFFFFF, i2 = 0x7FFFFFFF;
        #pragma unroll 4
        for (int j = 0; j < 512; ++j){
            float4 qa = ptq[j];
            float sc = fmaf(px, qa.x, fmaf(py, qa.y, fmaf(pz, qa.z, -qa.w)));
            if (__any(sc >= M2)){
                int sg = sQ + j;
                i0 = min(i0, sc == M0 ? sg : 0x7FFFFFFF);
                i1 = min(i1, sc == M1 ? sg : 0x7FFFFFFF);
                i2 = min(i2, sc == M2 ? sg : 0x7FFFFFFF);
            }
        }
        #pragma unroll
        for (int m = 1; m <= 2; m <<= 1){
            i0 = min(i0, __shfl_xor(i0, m));
            i1 = min(i1, __shfl_xor(i1, m));
            i2 = min(i2, __shfl_xor(i2, m));
        }

        if (M0 == M1 || M1 == M2){
            float L0 = -3.4e38f, L1 = -3.4e38f, L2 = -3.4e38f;
            int K0 = 0x7FFFFFFF, K1 = 0x7FFFFFFF, K2 = 0x7FFFFFFF;
            for (int j = 0; j < 512; ++j){
                float4 qa = ptq[j];
                float sc = fmaf(px, qa.x, fmaf(py, qa.y, fmaf(pz, qa.z, -qa.w)));
                INSL(sc, sQ + j);
            }
            #pragma unroll
            for (int m = 1; m <= 2; m <<= 1){
                float e0=__shfl_xor(L0,m), e1=__shfl_xor(L1,m), e2=__shfl_xor(L2,m);
                int   k0=__shfl_xor(K0,m), k1=__shfl_xor(K1,m), k2=__shfl_xor(K2,m);
                INSL(e0, k0); INSL(e1, k1); INSL(e2, k2);
            }
            i0 = K0; i1 = K1; i2 = K2;
        }

        if (q == 0){
            float d0 = fmaf(-2.f, M0, n1);
            float d1 = fmaf(-2.f, M1, n1);
            float d2 = fmaf(-2.f, M2, n1);
            float r0 = 1.f/(d0+1e-8f), r1 = 1.f/(d1+1e-8f), r2 = 1.f/(d2+1e-8f);
            float inv = 1.f/(r0+r1+r2);
            size_t base = (size_t)b*N_ + n;
            nn_idx4[base] = make_int4(i0, i1, i2, 0);
            nn_w4[base]   = make_float4(r0*inv, r1*inv, r2*inv, 0.f);
        }
    } else if (bid < 1024 + 4096){
        // ================= k_p2t (byte-identical body) =================
        float (*tt)[33] = (float(*)[33])smem;
        int pid = bid - 1024;
        int b = pid >> 9, s0 = (pid & 63) * 32, d0 = ((pid >> 6) & 7) * 32;
        int r = t >> 3, c4 = (t & 7) * 4;
        const float* src = p2 + (((size_t)b*D2_ + d0 + r) * S_ + s0 + c4);
        float4 v = *(const float4*)src;
        tt[r][c4+0]=v.x; tt[r][c4+1]=v.y; tt[r][c4+2]=v.z; tt[r][c4+3]=v.w;
        __syncthreads();
        ushort4 o;
        o.x = f2bf(tt[c4+0][r]); o.y = f2bf(tt[c4+1][r]);
        o.z = f2bf(tt[c4+2][r]); o.w = f2bf(tt[c4+3][r]);
        u16* dst = p2t + (((size_t)b*S_ + s0 + r) * D2_ + d0 + c4);
        *(ushort4*)dst = o;
    } else {
        // ================= k_prep_w (byte-identical body) =================
        int i = (bid - 5120) * 256 + t;
        if (i < C1_*CIN_) w1bf[i] = f2bf(w1[i]);
        if (i < C2_*C1_)  w2bf[i] = f2bf(w2[i]);
    }
}

// LDS swizzles: Xt row=768B, Zt row=512B
#define SWZ(nrow, kbyte)  ((((nrow)*768 + (kbyte))) ^ (((nrow)&7)<<4))
#define SWZ2(nrow, kbyte) ((((nrow)*512 + (kbyte))) ^ (((nrow)&7)<<4))

// ---------------- conv1 v4: 64-pt tile, 48KB LDS -> 2 blocks/CU (build/compute overlap) ----------------
// Round-15 analysis: v3's 96KB tile = 1 block/CU, build and MFMA strictly serial.
// v4 halves the tile: 48KB LDS + 128 VGPR = exactly 2 co-resident 8-wave blocks/CU;
// block A's MFMA overlaps block B's latency-bound gather (m114 co-scheduling).
// W reloads double (L2-resident, ~3us hidden). Register phases unchanged -> spill-free.
__global__ __launch_bounds__(512, 2)
void k_conv1(const u16* __restrict__ w1bf,
    const float* __restrict__ points1, const u16* __restrict__ p2t,
    const int4* __restrict__ nn_idx4, const float4* __restrict__ nn_w4,
    u16* __restrict__ y1, float* __restrict__ part1){
    __shared__ char sm[48*1024];
    int t = threadIdx.x;
    int wave = t >> 6, lane = t & 63;
    int b = blockIdx.y, n0g = blockIdx.x * 64;
    const int nlo = lane & 15, nhi = lane >> 4;
    const int g8 = t & 15, pr = t >> 4;   // phase A roles: 8-ch group, row-pair
    const int rb = t >> 3, q8 = t & 7;    // phase B roles: row, 32-ch group

    // ---- build the 64-row tile (transient registers only)
    {
        char* X = sm;
        float2 va2[8];
        const float* pA = points1 + ((size_t)b*D1_ + g8*8)*N_ + n0g + pr*2;
        #pragma unroll
        for (int j = 0; j < 8; ++j) va2[j] = *(const float2*)(pA + (size_t)j*N_);
        size_t nb = (size_t)b*N_ + n0g + rb;
        int4 nid = nn_idx4[nb];
        float4 nw = nn_w4[nb];
        const u16* r0 = p2t + ((size_t)b*S_ + nid.x)*D2_ + q8*32;
        const u16* r1 = p2t + ((size_t)b*S_ + nid.y)*D2_ + q8*32;
        const u16* r2 = p2t + ((size_t)b*S_ + nid.z)*D2_ + q8*32;
        uint4 uB[12];
        #pragma unroll
        for (int c = 0; c < 4; ++c){
            uB[c]   = *(const uint4*)(r0 + c*8);
            uB[4+c] = *(const uint4*)(r1 + c*8);
            uB[8+c] = *(const uint4*)(r2 + c*8);
        }
        #pragma unroll
        for (int e = 0; e < 2; ++e){
            u16 h[8];
            #pragma unroll
            for (int j = 0; j < 8; ++j) h[j] = f2bf(e ? va2[j].y : va2[j].x);
            *(uint4*)(X + SWZ(pr*2+e, g8*16)) = pack8(h);
        }
        #pragma unroll
        for (int c = 0; c < 4; ++c){
            float f0[8], f1[8], f2v[8];
            EXT8(f0, uB[c]); EXT8(f1, uB[4+c]); EXT8(f2v, uB[8+c]);
            u16 h[8];
            #pragma unroll
            for (int e = 0; e < 8; ++e)
                h[e] = f2bf(fmaf(nw.x, f0[e], fmaf(nw.y, f1[e], nw.z*f2v[e])));
            *(uint4*)(X + SWZ(rb, (128 + q8*32 + c*8)*2)) = pack8(h);
        }
    }
    __syncthreads();

    // ---- two channel passes; wfr reloaded per pass (L2-resident W1)
    int blk = blockIdx.y * gridDim.x + blockIdx.x;   // 0..1023
    #pragma unroll 1
    for (int pass = 0; pass < 2; ++pass){
        bf16x8 wfr[12];
        {
            const u16* wb = w1bf + ((size_t)(pass*128 + wave*16 + nlo))*CIN_ + nhi*8;
            #pragma unroll
            for (int ks = 0; ks < 12; ++ks) wfr[ks] = *(const bf16x8*)(wb + ks*32);
        }
        float s1a[4] = {0,0,0,0}, s2a[4] = {0,0,0,0};
        #pragma unroll 1
        for (int rowg = 0; rowg < 4; ++rowg){
            int nrow = rowg*16 + nlo;
            f32x4 acc = {0.f,0.f,0.f,0.f};
            #pragma unroll
            for (int hf = 0; hf < 2; ++hf){
                bf16x8 xf[6];
                #pragma unroll
                for (int k6 = 0; k6 < 6; ++k6)
                    xf[k6] = *(const bf16x8*)(sm + SWZ(nrow, (hf*6+k6)*64 + nhi*16));
                #pragma unroll
                for (int k6 = 0; k6 < 6; ++k6)
                    acc = __builtin_amdgcn_mfma_f32_16x16x32_bf16(wfr[hf*6+k6], xf[k6], acc, 0,0,0);
            }
            int n = n0g + nrow;
            u16 h[4];
            #pragma unroll
            for (int r = 0; r < 4; ++r){
                h[r] = f2bf(acc[r]);
                s1a[r] += acc[r]; s2a[r] += acc[r]*acc[r];
            }
            uint2 p;
            p.x = (u32)h[0] | ((u32)h[1]<<16); p.y = (u32)h[2] | ((u32)h[3]<<16);
            *(uint2*)(y1 + ((size_t)b*N_ + n)*C1_ + pass*128 + wave*16 + nhi*4) = p;
        }
        // BN1 partials for this pass's channels
        #pragma unroll
        for (int r = 0; r < 4; ++r){
            float a = s1a[r], qv = s2a[r];
            #pragma unroll
            for (int m = 1; m <= 8; m <<= 1){ a += __shfl_xor(a, m); qv += __shfl_xor(qv, m); }
            if (nlo == 0){
                int ch = pass*128 + wave*16 + nhi*4 + r;
                part1[(size_t)blk*C1_ + ch] = a;
                part1[(size_t)1024*C1_ + (size_t)blk*C1_ + ch] = qv;
            }
        }
    }
}

// ---------------- conv2: W-stationary, z = relu(bn1(y1)) on the fly ----------------
__global__ __launch_bounds__(512, 2) void k_conv2(const u16* __restrict__ w2bf,
    const u16* __restrict__ y1, const float* __restrict__ a1c1,
    u16* __restrict__ z2bf, float* __restrict__ part2){
    __shared__ char sm[64*1024];
    int t = threadIdx.x;
    int wave = t >> 6, lane = t & 63;
    int b = blockIdx.y, n0g = blockIdx.x * 256;
    const int nlo = lane & 15, nhi = lane >> 4;

    bf16x8 wfr[8];
    {
        const u16* wb = w2bf + ((size_t)(wave*16 + nlo))*C1_ + nhi*8;
        #pragma unroll
        for (int ks = 0; ks < 8; ++ks) wfr[ks] = *(const bf16x8*)(wb + ks*32);
    }

    const int r2 = t >> 4, q16 = t & 15;   // build roles: row-pair, 16-ch group
    float la8[16], lc8[16];
    {
        const float* ap = a1c1 + q16*16;
        #pragma unroll
        for (int c = 0; c < 4; ++c){
            *(float4*)(la8 + c*4) = *(const float4*)(ap + c*4);
            *(float4*)(lc8 + c*4) = *(const float4*)(ap + 256 + c*4);
        }
    }

    uint4 uy[4];
    auto ISSUE_Y = [&](int s){
        const u16* yp = y1 + ((size_t)b*N_ + n0g + s*64 + r2*2)*C1_ + q16*16;
        #pragma unroll
        for (int e = 0; e < 2; ++e)
            #pragma unroll
            for (int c = 0; c < 2; ++c)
                uy[e*2+c] = *(const uint4*)(yp + (size_t)e*C1_ + c*8);
    };
    auto COMBINE = [&](char* Z){
        #pragma unroll
        for (int e = 0; e < 2; ++e)
            #pragma unroll
            for (int c = 0; c < 2; ++c){
                float f[8]; EXT8(f, uy[e*2+c]);
                u16 h[8];
                #pragma unroll
                for (int k = 0; k < 8; ++k){
                    float z = fmaf(la8[c*8+k], f[k], lc8[c*8+k]);
                    h[k] = f2bf(z > 0.f ? z : 0.f);
                }
                *(uint4*)(Z + SWZ2(r2*2+e, q16*32 + c*16)) = pack8(h);
            }
    };

    char* Zc = sm;
    char* Zn = sm + 32*1024;

    ISSUE_Y(0);
    COMBINE(Zc);
    __syncthreads();

    float s1a[4] = {0,0,0,0}, s2a[4] = {0,0,0,0};
    const int kgB = nhi*16;

    #pragma unroll 1
    for (int s = 0; s < NSUB_; ++s){
        if (s+1 < NSUB_) ISSUE_Y(s+1);
        #pragma unroll
        for (int rowg = 0; rowg < 4; ++rowg){
            int nrow = rowg*16 + nlo;
            f32x4 acc = {0.f,0.f,0.f,0.f};
            #pragma unroll
            for (int hf = 0; hf < 2; ++hf){
                bf16x8 xf[4];
                #pragma unroll
                for (int k4 = 0; k4 < 4; ++k4)
                    xf[k4] = *(const bf16x8*)(Zc + SWZ2(nrow, (hf*4+k4)*64 + kgB));
                #pragma unroll
                for (int k4 = 0; k4 < 4; ++k4)
                    acc = __builtin_amdgcn_mfma_f32_16x16x32_bf16(wfr[hf*4+k4], xf[k4], acc, 0,0,0);
            }
            int n = n0g + s*64 + nrow;
            u16 h[4];
            #pragma unroll
            for (int r = 0; r < 4; ++r){
                h[r] = f2bf(acc[r]);
                s1a[r] += acc[r]; s2a[r] += acc[r]*acc[r];
            }
            uint2 p;
            p.x = (u32)h[0] | ((u32)h[1]<<16); p.y = (u32)h[2] | ((u32)h[3]<<16);
            *(uint2*)(z2bf + ((size_t)b*N_ + n)*C2_ + wave*16 + nhi*4) = p;
        }
        if (s+1 < NSUB_) COMBINE(Zn);
        __syncthreads();
        char* tmp = Zc; Zc = Zn; Zn = tmp;
    }

    int blk = blockIdx.y * gridDim.x + blockIdx.x;
    #pragma unroll
    for (int r = 0; r < 4; ++r){
        float a = s1a[r], qv = s2a[r];
        #pragma unroll
        for (int m = 1; m <= 8; m <<= 1){ a += __shfl_xor(a, m); qv += __shfl_xor(qv, m); }
        if (nlo == 0){
            int ch = wave*16 + nhi*4 + r;
            part2[(size_t)blk*C2_ + ch] = a;
            part2[(size_t)256*C2_ + (size_t)blk*C2_ + ch] = qv;
        }
    }
}

// ---------------- finalize BN stats ----------------
__global__ void k_finalize(const float* __restrict__ part, int C, int NB, float count,
                           const float* __restrict__ gamma, const float* __restrict__ beta,
                           float* __restrict__ ac){
    int o = blockIdx.x, t = threadIdx.x;
    float s1 = 0.f, s2 = 0.f;
    for (int i = t; i < NB; i += 256){
        s1 += part[(size_t)i*C + o];
        s2 += part[(size_t)NB*C + (size_t)i*C + o];
    }
    #pragma unroll
    for (int m = 1; m < 64; m <<= 1){ s1 += __shfl_xor(s1, m); s2 += __shfl_xor(s2, m); }
    __shared__ float ls[8];
    int wave = t >> 6, lane = t & 63;
    if (lane == 0){ ls[wave] = s1; ls[4+wave] = s2; }
    __syncthreads();
    if (t == 0){
        s1 = ls[0]+ls[1]+ls[2]+ls[3];
        s2 = ls[4]+ls[5]+ls[6]+ls[7];
        float mean = s1 / count;
        float var  = s2 / count - mean*mean;
        float inv  = rsqrtf(var + 1e-5f);
        float a = gamma[o] * inv;
        ac[o] = a;
        ac[C + o] = beta[o] - mean*a;
    }
}

// ---------------- apply BN2+ReLU with transpose: z2bf [b][n][ch] -> out [b][ch][n] f32 ----------------
__global__ __launch_bounds__(256) void k_apply(const u16* __restrict__ z2bf,
                                               const float* __restrict__ a2c2,
                                               float* __restrict__ out){
    __shared__ float T[128][65];
    __shared__ float la[C2_], lc[C2_];
    int b = blockIdx.y, n0 = blockIdx.x * 64;
    int t = threadIdx.x;
    if (t < C2_){ la[t] = a2c2[t]; lc[t] = a2c2[C2_ + t]; }
    __syncthreads();
    int ck = t & 15, ng = t >> 4;
    #pragma unroll
    for (int g = 0; g < 4; ++g){
        int n = g*16 + ng;
        uint4 v = *(const uint4*)(z2bf + ((size_t)b*N_ + n0 + n)*C2_ + ck*8);
        float f[8]; EXT8(f, v);
        #pragma unroll
        for (int e = 0; e < 8; ++e){
            int ch = ck*8 + e;
            T[ch][n] = fmaxf(fmaf(la[ch], f[e], lc[ch]), 0.f);
        }
    }
    __syncthreads();
    #pragma unroll
    for (int g = 0; g < 8; ++g){
        int id = g*256 + t;
        int ch = id >> 4, f4 = id & 15;
        float4 o;
        o.x = T[ch][f4*4+0]; o.y = T[ch][f4*4+1];
        o.z = T[ch][f4*4+2]; o.w = T[ch][f4*4+3];
        *(float4*)(out + ((size_t)b*C2_ + ch)*N_ + n0 + f4*4) = o;
    }
}

extern "C" void kernel_launch(void* const* d_in, const int* in_sizes, int n_in,
                              void* d_out, int out_size, void* d_ws, size_t ws_size,
                              hipStream_t stream){
    const float* xyz1    = (const float*)d_in[0];
    const float* xyz2    = (const float*)d_in[1];
    const float* points1 = (const float*)d_in[2];
    const float* points2 = (const float*)d_in[3];
    const float* w1      = (const float*)d_in[4];
    const float* gamma1  = (const float*)d_in[6];
    const float* beta1   = (const float*)d_in[7];
    const float* w2      = (const float*)d_in[8];
    const float* gamma2  = (const float*)d_in[10];
    const float* beta2   = (const float*)d_in[11];
    float* outp = (float*)d_out;

    char* ws = (char*)d_ws;
    size_t off = 0;
    auto take = [&](size_t sz) -> void* {
        void* p = ws + off;
        off = (off + sz + 255) & ~(size_t)255;
        return p;
    };
    int4*   nn_idx4 = (int4*)  take((size_t)B_*N_*16);
    float4* nn_w4   = (float4*)take((size_t)B_*N_*16);
    u16*    w1bf    = (u16*)   take((size_t)C1_*CIN_*2);
    u16*    w2bf    = (u16*)   take((size_t)C2_*C1_*2);
    u16*    p2t     = (u16*)   take((size_t)B_*S_*D2_*2);
    u16*    y1      = (u16*)   take((size_t)B_*N_*C1_*2);
    u16*    z2bf    = (u16*)   take((size_t)B_*N_*C2_*2);
    float*  part1   = (float*) take((size_t)2*1024*C1_*4);
    float*  part2   = (float*) take((size_t)2*256*C2_*4);
    float*  a1c1    = (float*) take((size_t)2*C1_*4);
    float*  a2c2    = (float*) take((size_t)2*C2_*4);

    hipLaunchKernelGGL(k_pre, dim3(1024 + 4096 + 384), dim3(256), 0, stream,
                       xyz1, xyz2, points2, w1, w2, nn_idx4, nn_w4, p2t, w1bf, w2bf);
    hipLaunchKernelGGL(k_conv1, dim3(N_/64, B_), dim3(512), 0, stream,
                       w1bf, points1, p2t, nn_idx4, nn_w4, y1, part1);
    hipLaunchKernelGGL(k_finalize, dim3(C1_), dim3(256), 0, stream,
                       part1, C1_, 1024, (float)(B_*N_), gamma1, beta1, a1c1);
    hipLaunchKernelGGL(k_conv2, dim3(N_/256, B_), dim3(512), 0, stream,
                       w2bf, y1, a1c1, z2bf, part2);
    hipLaunchKernelGGL(k_finalize, dim3(C2_), dim3(256), 0, stream,
                       part2, C2_, 256, (float)(B_*N_), gamma2, beta2, a2c2);
    hipLaunchKernelGGL(k_apply, dim3(N_/64, B_), dim3(256), 0, stream, z2bf, a2c2, outp);
    (void)in_sizes; (void)n_in; (void)out_size; (void)ws_size; (void)d_in;
}

// Round 17
// 134.285 us; speedup vs baseline: 1.0363x; 1.0363x over previous
//
#include <hip/hip_runtime.h>
#include <stdint.h>

#define B_   8
#define N_   8192
#define S_   2048
#define D1_  128
#define D2_  256
#define CIN_ 384
#define C1_  256
#define C2_  128
#define NSUB_ 4

typedef uint16_t u16;
typedef uint32_t u32;
typedef __attribute__((ext_vector_type(8))) short bf16x8;
typedef __attribute__((ext_vector_type(4))) float f32x4;

static __device__ __forceinline__ u16 f2bf(float f){
    union { float f; u32 u; } v; v.f = f;
    u32 r = v.u + 0x7FFF + ((v.u >> 16) & 1);
    return (u16)(r >> 16);
}
static __device__ __forceinline__ float bf2f(u16 h){
    union { u32 u; float f; } v; v.u = ((u32)h) << 16;
    return v.f;
}
static __device__ __forceinline__ uint4 pack8(const u16 h[8]){
    uint4 u;
    u.x = (u32)h[0] | ((u32)h[1] << 16);
    u.y = (u32)h[2] | ((u32)h[3] << 16);
    u.z = (u32)h[4] | ((u32)h[5] << 16);
    u.w = (u32)h[6] | ((u32)h[7] << 16);
    return u;
}
#define EXT8(dst, u) { dst[0]=bf2f((u16)(u).x); dst[1]=bf2f((u16)((u).x>>16)); \
                       dst[2]=bf2f((u16)(u).y); dst[3]=bf2f((u16)((u).y>>16)); \
                       dst[4]=bf2f((u16)(u).z); dst[5]=bf2f((u16)((u).z>>16)); \
                       dst[6]=bf2f((u16)(u).w); dst[7]=bf2f((u16)((u).w>>16)); }

static __device__ __forceinline__ float med3f(float a, float b, float c){
    float d;
    asm("v_med3_f32 %0, %1, %2, %3" : "=v"(d) : "v"(a), "v"(b), "v"(c));
    return d;
}

// ---------------- fused pre-pass: k_nn (blocks 0..1023) + p2t (1024..5119) + prep_w (5120..5503) ----------------
// k_nn v5.1: + per-lane pass-2 skip. A segment can contain a global-top-3 candidate
// only if its local max A0loc >= M2 (any match has sc >= M2 <= A0loc). P(skip) ~ 42%
// -> EXEC-masked lanes issue no LDS requests -> pass-2 LDS traffic (~half of 4.3GB)
// drops ~40%. Selection math bit-identical (round-3 lesson). Round-16: conv1 v4
// (2 blk/CU overlap) regressed -> conv1 reverted to v3.
#define INSV(sc) do{ \
    float t2_ = med3f(A1, A2, (sc)); \
    float t1_ = med3f(A0, A1, (sc)); \
    A0 = fmaxf(A0, (sc)); \
    A1 = t1_; A2 = t2_; \
}while(0)
#define INSVB(sc) do{ \
    float t2_ = med3f(Bb1, Bb2, (sc)); \
    float t1_ = med3f(Bb0, Bb1, (sc)); \
    Bb0 = fmaxf(Bb0, (sc)); \
    Bb1 = t1_; Bb2 = t2_; \
}while(0)
#define INSL(sc, si) do{ \
    bool c0 = ((sc) > L0) || ((sc) == L0 && (si) < K0); \
    bool c1 = ((sc) > L1) || ((sc) == L1 && (si) < K1); \
    bool c2 = ((sc) > L2) || ((sc) == L2 && (si) < K2); \
    int K2n = c2 ? (c1 ? K1 : (si)) : K2; \
    int K1n = c1 ? (c0 ? K0 : (si)) : K1; \
    int K0n = c0 ? (si) : K0; \
    float T2 = med3f(L1, L2, (sc)); \
    float T1 = med3f(L0, L1, (sc)); \
    L0 = fmaxf(L0, (sc)); \
    L1 = T1; L2 = T2; K0 = K0n; K1 = K1n; K2 = K2n; \
}while(0)

__global__ __launch_bounds__(256) void k_pre(const float* __restrict__ xyz1,
                                             const float* __restrict__ xyz2,
                                             const float* __restrict__ p2,
                                             const float* __restrict__ w1,
                                             const float* __restrict__ w2,
                                             int4* __restrict__ nn_idx4, float4* __restrict__ nn_w4,
                                             u16* __restrict__ p2t, u16* __restrict__ w1bf,
                                             u16* __restrict__ w2bf){
    __shared__ __attribute__((aligned(16))) char smem[4*513*16];
    int bid = blockIdx.x;
    int t = threadIdx.x;

    if (bid < 1024){
        // ================= k_nn v5.1 =================
        float4* pt = (float4*)smem;          // [4*513], quarter q at pt + q*513
        int b = bid >> 7;
        int bx = bid & 127;
        const float* xb = xyz2 + (size_t)b*3*S_;
        for (int i = t; i < S_; i += 256){
            float x = xb[i], y = xb[S_ + i], z = xb[2*S_ + i];
            float hw = 0.5f*(x*x + y*y + z*z);
            pt[(i >> 9)*513 + (i & 511)] = make_float4(x, y, z, hw);
        }
        __syncthreads();
        int nl = t >> 2, q = t & 3;
        int n = bx * 64 + nl;
        const float* x1b = xyz1 + (size_t)b*3*N_;
        float px = x1b[n], py = x1b[N_ + n], pz = x1b[2*N_ + n];
        float n1 = px*px + py*py + pz*pz;
        const float4* ptq = pt + q*513;
        const int sQ = q * 512;

        // ---- pass 1: top-3 values only (2 interleaved chains)
        float A0 = -3.4e38f, A1 = -3.4e38f, A2 = -3.4e38f;
        float Bb0 = -3.4e38f, Bb1 = -3.4e38f, Bb2 = -3.4e38f;
        #pragma unroll 4
        for (int j = 0; j < 512; j += 2){
            float4 qa = ptq[j];
            float4 qb = ptq[j+1];
            float sa = fmaf(px, qa.x, fmaf(py, qa.y, fmaf(pz, qa.z, -qa.w)));
            float sb = fmaf(px, qb.x, fmaf(py, qb.y, fmaf(pz, qb.z, -qb.w)));
            INSV(sa);
            INSVB(sb);
        }
        INSV(Bb0); INSV(Bb1); INSV(Bb2);
        const float A0loc = A0;              // this segment's max (pre cross-thread merge)
        #pragma unroll
        for (int m = 1; m <= 2; m <<= 1){
            float e0=__shfl_xor(A0,m), e1=__shfl_xor(A1,m), e2=__shfl_xor(A2,m);
            INSV(e0); INSV(e1); INSV(e2);
        }
        const float M0 = A0, M1 = A1, M2 = A2;

        // ---- pass 2: guarded index recovery; whole-segment skip if A0loc < M2
        int i0 = 0x7FFFFFFF, i1 = 0x7FFFFFFF, i2 = 0x7FFFFFFF;
        if (A0loc >= M2){
            #pragma unroll 4
            for (int j = 0; j < 512; ++j){
                float4 qa = ptq[j];
                float sc = fmaf(px, qa.x, fmaf(py, qa.y, fmaf(pz, qa.z, -qa.w)));
                if (__any(sc >= M2)){
                    int sg = sQ + j;
                    i0 = min(i0, sc == M0 ? sg : 0x7FFFFFFF);
                    i1 = min(i1, sc == M1 ? sg : 0x7FFFFFFF);
                    i2 = min(i2, sc == M2 ? sg : 0x7FFFFFFF);
                }
            }
        }
        #pragma unroll
        for (int m = 1; m <= 2; m <<= 1){
            i0 = min(i0, __shfl_xor(i0, m));
            i1 = min(i1, __shfl_xor(i1, m));
            i2 = min(i2, __shfl_xor(i2, m));
        }

        // ---- duplicate-value fixup (group-uniform condition; ~never taken)
        if (M0 == M1 || M1 == M2){
            float L0 = -3.4e38f, L1 = -3.4e38f, L2 = -3.4e38f;
            int K0 = 0x7FFFFFFF, K1 = 0x7FFFFFFF, K2 = 0x7FFFFFFF;
            for (int j = 0; j < 512; ++j){
                float4 qa = ptq[j];
                float sc = fmaf(px, qa.x, fmaf(py, qa.y, fmaf(pz, qa.z, -qa.w)));
                INSL(sc, sQ + j);
            }
            #pragma unroll
            for (int m = 1; m <= 2; m <<= 1){
                float e0=__shfl_xor(L0,m), e1=__shfl_xor(L1,m), e2=__shfl_xor(L2,m);
                int   k0=__shfl_xor(K0,m), k1=__shfl_xor(K1,m), k2=__shfl_xor(K2,m);
                INSL(e0, k0); INSL(e1, k1); INSL(e2, k2);
            }
            i0 = K0; i1 = K1; i2 = K2;
        }

        if (q == 0){
            float d0 = fmaf(-2.f, M0, n1);
            float d1 = fmaf(-2.f, M1, n1);
            float d2 = fmaf(-2.f, M2, n1);
            float r0 = 1.f/(d0+1e-8f), r1 = 1.f/(d1+1e-8f), r2 = 1.f/(d2+1e-8f);
            float inv = 1.f/(r0+r1+r2);
            size_t base = (size_t)b*N_ + n;
            nn_idx4[base] = make_int4(i0, i1, i2, 0);
            nn_w4[base]   = make_float4(r0*inv, r1*inv, r2*inv, 0.f);
        }
    } else if (bid < 1024 + 4096){
        // ================= k_p2t (byte-identical body) =================
        float (*tt)[33] = (float(*)[33])smem;
        int pid = bid - 1024;
        int b = pid >> 9, s0 = (pid & 63) * 32, d0 = ((pid >> 6) & 7) * 32;
        int r = t >> 3, c4 = (t & 7) * 4;
        const float* src = p2 + (((size_t)b*D2_ + d0 + r) * S_ + s0 + c4);
        float4 v = *(const float4*)src;
        tt[r][c4+0]=v.x; tt[r][c4+1]=v.y; tt[r][c4+2]=v.z; tt[r][c4+3]=v.w;
        __syncthreads();
        ushort4 o;
        o.x = f2bf(tt[c4+0][r]); o.y = f2bf(tt[c4+1][r]);
        o.z = f2bf(tt[c4+2][r]); o.w = f2bf(tt[c4+3][r]);
        u16* dst = p2t + (((size_t)b*S_ + s0 + r) * D2_ + d0 + c4);
        *(ushort4*)dst = o;
    } else {
        // ================= k_prep_w (byte-identical body) =================
        int i = (bid - 5120) * 256 + t;
        if (i < C1_*CIN_) w1bf[i] = f2bf(w1[i]);
        if (i < C2_*C1_)  w2bf[i] = f2bf(w2[i]);
    }
}

// LDS swizzles: Xt row=768B, Zt row=512B
#define SWZ(nrow, kbyte)  ((((nrow)*768 + (kbyte))) ^ (((nrow)&7)<<4))
#define SWZ2(nrow, kbyte) ((((nrow)*512 + (kbyte))) ^ (((nrow)&7)<<4))

// ---------------- conv1 v3 (reverted from v4; v4's 2-blk/CU overlap regressed) ----------------
__global__ __launch_bounds__(512, 2)
void k_conv1(const u16* __restrict__ w1bf,
    const float* __restrict__ points1, const u16* __restrict__ p2t,
    const int4* __restrict__ nn_idx4, const float4* __restrict__ nn_w4,
    u16* __restrict__ y1, float* __restrict__ part1){
    __shared__ char sm[96*1024];
    int t = threadIdx.x;
    int wave = t >> 6, lane = t & 63;
    int b = blockIdx.y, n0g = blockIdx.x * 128;
    const int nlo = lane & 15, nhi = lane >> 4;
    const int g8 = t & 15, pr = t >> 4;   // phase A roles: 8-ch group, row-pair
    const int rb = t >> 3, q8 = t & 7;    // phase B roles: row, 32-ch group

    // ---- build both 64-row subtiles (sequential; transient registers only)
    #pragma unroll 1
    for (int sub = 0; sub < 2; ++sub){
        char* X = sm + sub*48*1024;
        float2 va2[8];
        const float* pA = points1 + ((size_t)b*D1_ + g8*8)*N_ + n0g + sub*64 + pr*2;
        #pragma unroll
        for (int j = 0; j < 8; ++j) va2[j] = *(const float2*)(pA + (size_t)j*N_);
        size_t nb = (size_t)b*N_ + n0g + sub*64 + rb;
        int4 nid = nn_idx4[nb];
        float4 nw = nn_w4[nb];
        const u16* r0 = p2t + ((size_t)b*S_ + nid.x)*D2_ + q8*32;
        const u16* r1 = p2t + ((size_t)b*S_ + nid.y)*D2_ + q8*32;
        const u16* r2 = p2t + ((size_t)b*S_ + nid.z)*D2_ + q8*32;
        uint4 uB[12];
        #pragma unroll
        for (int c = 0; c < 4; ++c){
            uB[c]   = *(const uint4*)(r0 + c*8);
            uB[4+c] = *(const uint4*)(r1 + c*8);
            uB[8+c] = *(const uint4*)(r2 + c*8);
        }
        #pragma unroll
        for (int e = 0; e < 2; ++e){
            u16 h[8];
            #pragma unroll
            for (int j = 0; j < 8; ++j) h[j] = f2bf(e ? va2[j].y : va2[j].x);
            *(uint4*)(X + SWZ(pr*2+e, g8*16)) = pack8(h);
        }
        #pragma unroll
        for (int c = 0; c < 4; ++c){
            float f0[8], f1[8], f2v[8];
            EXT8(f0, uB[c]); EXT8(f1, uB[4+c]); EXT8(f2v, uB[8+c]);
            u16 h[8];
            #pragma unroll
            for (int e = 0; e < 8; ++e)
                h[e] = f2bf(fmaf(nw.x, f0[e], fmaf(nw.y, f1[e], nw.z*f2v[e])));
            *(uint4*)(X + SWZ(rb, (128 + q8*32 + c*8)*2)) = pack8(h);
        }
    }
    __syncthreads();

    // ---- two channel passes; wfr reloaded per pass (L2-resident W1)
    int blk = blockIdx.y * gridDim.x + blockIdx.x;
    #pragma unroll 1
    for (int pass = 0; pass < 2; ++pass){
        bf16x8 wfr[12];
        {
            const u16* wb = w1bf + ((size_t)(pass*128 + wave*16 + nlo))*CIN_ + nhi*8;
            #pragma unroll
            for (int ks = 0; ks < 12; ++ks) wfr[ks] = *(const bf16x8*)(wb + ks*32);
        }
        float s1a[4] = {0,0,0,0}, s2a[4] = {0,0,0,0};
        #pragma unroll 1
        for (int sub = 0; sub < 2; ++sub){
            char* X = sm + sub*48*1024;
            #pragma unroll 1
            for (int rowg = 0; rowg < 4; ++rowg){
                int nrow = rowg*16 + nlo;
                f32x4 acc = {0.f,0.f,0.f,0.f};
                #pragma unroll
                for (int hf = 0; hf < 2; ++hf){
                    bf16x8 xf[6];
                    #pragma unroll
                    for (int k6 = 0; k6 < 6; ++k6)
                        xf[k6] = *(const bf16x8*)(X + SWZ(nrow, (hf*6+k6)*64 + nhi*16));
                    #pragma unroll
                    for (int k6 = 0; k6 < 6; ++k6)
                        acc = __builtin_amdgcn_mfma_f32_16x16x32_bf16(wfr[hf*6+k6], xf[k6], acc, 0,0,0);
                }
                int n = n0g + sub*64 + nrow;
                u16 h[4];
                #pragma unroll
                for (int r = 0; r < 4; ++r){
                    h[r] = f2bf(acc[r]);
                    s1a[r] += acc[r]; s2a[r] += acc[r]*acc[r];
                }
                uint2 p;
                p.x = (u32)h[0] | ((u32)h[1]<<16); p.y = (u32)h[2] | ((u32)h[3]<<16);
                *(uint2*)(y1 + ((size_t)b*N_ + n)*C1_ + pass*128 + wave*16 + nhi*4) = p;
            }
        }
        // BN1 partials for this pass's channels
        #pragma unroll
        for (int r = 0; r < 4; ++r){
            float a = s1a[r], qv = s2a[r];
            #pragma unroll
            for (int m = 1; m <= 8; m <<= 1){ a += __shfl_xor(a, m); qv += __shfl_xor(qv, m); }
            if (nlo == 0){
                int ch = pass*128 + wave*16 + nhi*4 + r;
                part1[(size_t)blk*C1_ + ch] = a;
                part1[(size_t)512*C1_ + (size_t)blk*C1_ + ch] = qv;
            }
        }
    }
}

// ---------------- conv2: W-stationary, z = relu(bn1(y1)) on the fly ----------------
__global__ __launch_bounds__(512, 2) void k_conv2(const u16* __restrict__ w2bf,
    const u16* __restrict__ y1, const float* __restrict__ a1c1,
    u16* __restrict__ z2bf, float* __restrict__ part2){
    __shared__ char sm[64*1024];
    int t = threadIdx.x;
    int wave = t >> 6, lane = t & 63;
    int b = blockIdx.y, n0g = blockIdx.x * 256;
    const int nlo = lane & 15, nhi = lane >> 4;

    bf16x8 wfr[8];
    {
        const u16* wb = w2bf + ((size_t)(wave*16 + nlo))*C1_ + nhi*8;
        #pragma unroll
        for (int ks = 0; ks < 8; ++ks) wfr[ks] = *(const bf16x8*)(wb + ks*32);
    }

    const int r2 = t >> 4, q16 = t & 15;   // build roles: row-pair, 16-ch group
    float la8[16], lc8[16];
    {
        const float* ap = a1c1 + q16*16;
        #pragma unroll
        for (int c = 0; c < 4; ++c){
            *(float4*)(la8 + c*4) = *(const float4*)(ap + c*4);
            *(float4*)(lc8 + c*4) = *(const float4*)(ap + 256 + c*4);
        }
    }

    uint4 uy[4];
    auto ISSUE_Y = [&](int s){
        const u16* yp = y1 + ((size_t)b*N_ + n0g + s*64 + r2*2)*C1_ + q16*16;
        #pragma unroll
        for (int e = 0; e < 2; ++e)
            #pragma unroll
            for (int c = 0; c < 2; ++c)
                uy[e*2+c] = *(const uint4*)(yp + (size_t)e*C1_ + c*8);
    };
    auto COMBINE = [&](char* Z){
        #pragma unroll
        for (int e = 0; e < 2; ++e)
            #pragma unroll
            for (int c = 0; c < 2; ++c){
                float f[8]; EXT8(f, uy[e*2+c]);
                u16 h[8];
                #pragma unroll
                for (int k = 0; k < 8; ++k){
                    float z = fmaf(la8[c*8+k], f[k], lc8[c*8+k]);
                    h[k] = f2bf(z > 0.f ? z : 0.f);
                }
                *(uint4*)(Z + SWZ2(r2*2+e, q16*32 + c*16)) = pack8(h);
            }
    };

    char* Zc = sm;
    char* Zn = sm + 32*1024;

    ISSUE_Y(0);
    COMBINE(Zc);
    __syncthreads();

    float s1a[4] = {0,0,0,0}, s2a[4] = {0,0,0,0};
    const int kgB = nhi*16;

    #pragma unroll 1
    for (int s = 0; s < NSUB_; ++s){
        if (s+1 < NSUB_) ISSUE_Y(s+1);
        #pragma unroll
        for (int rowg = 0; rowg < 4; ++rowg){
            int nrow = rowg*16 + nlo;
            f32x4 acc = {0.f,0.f,0.f,0.f};
            #pragma unroll
            for (int hf = 0; hf < 2; ++hf){
                bf16x8 xf[4];
                #pragma unroll
                for (int k4 = 0; k4 < 4; ++k4)
                    xf[k4] = *(const bf16x8*)(Zc + SWZ2(nrow, (hf*4+k4)*64 + kgB));
                #pragma unroll
                for (int k4 = 0; k4 < 4; ++k4)
                    acc = __builtin_amdgcn_mfma_f32_16x16x32_bf16(wfr[hf*4+k4], xf[k4], acc, 0,0,0);
            }
            int n = n0g + s*64 + nrow;
            u16 h[4];
            #pragma unroll
            for (int r = 0; r < 4; ++r){
                h[r] = f2bf(acc[r]);
                s1a[r] += acc[r]; s2a[r] += acc[r]*acc[r];
            }
            uint2 p;
            p.x = (u32)h[0] | ((u32)h[1]<<16); p.y = (u32)h[2] | ((u32)h[3]<<16);
            *(uint2*)(z2bf + ((size_t)b*N_ + n)*C2_ + wave*16 + nhi*4) = p;
        }
        if (s+1 < NSUB_) COMBINE(Zn);
        __syncthreads();
        char* tmp = Zc; Zc = Zn; Zn = tmp;
    }

    int blk = blockIdx.y * gridDim.x + blockIdx.x;
    #pragma unroll
    for (int r = 0; r < 4; ++r){
        float a = s1a[r], qv = s2a[r];
        #pragma unroll
        for (int m = 1; m <= 8; m <<= 1){ a += __shfl_xor(a, m); qv += __shfl_xor(qv, m); }
        if (nlo == 0){
            int ch = wave*16 + nhi*4 + r;
            part2[(size_t)blk*C2_ + ch] = a;
            part2[(size_t)256*C2_ + (size_t)blk*C2_ + ch] = qv;
        }
    }
}

// ---------------- finalize BN stats ----------------
__global__ void k_finalize(const float* __restrict__ part, int C, int NB, float count,
                           const float* __restrict__ gamma, const float* __restrict__ beta,
                           float* __restrict__ ac){
    int o = blockIdx.x, t = threadIdx.x;
    float s1 = 0.f, s2 = 0.f;
    for (int i = t; i < NB; i += 256){
        s1 += part[(size_t)i*C + o];
        s2 += part[(size_t)NB*C + (size_t)i*C + o];
    }
    #pragma unroll
    for (int m = 1; m < 64; m <<= 1){ s1 += __shfl_xor(s1, m); s2 += __shfl_xor(s2, m); }
    __shared__ float ls[8];
    int wave = t >> 6, lane = t & 63;
    if (lane == 0){ ls[wave] = s1; ls[4+wave] = s2; }
    __syncthreads();
    if (t == 0){
        s1 = ls[0]+ls[1]+ls[2]+ls[3];
        s2 = ls[4]+ls[5]+ls[6]+ls[7];
        float mean = s1 / count;
        float var  = s2 / count - mean*mean;
        float inv  = rsqrtf(var + 1e-5f);
        float a = gamma[o] * inv;
        ac[o] = a;
        ac[C + o] = beta[o] - mean*a;
    }
}

// ---------------- apply BN2+ReLU with transpose: z2bf [b][n][ch] -> out [b][ch][n] f32 ----------------
__global__ __launch_bounds__(256) void k_apply(const u16* __restrict__ z2bf,
                                               const float* __restrict__ a2c2,
                                               float* __restrict__ out){
    __shared__ float T[128][65];
    __shared__ float la[C2_], lc[C2_];
    int b = blockIdx.y, n0 = blockIdx.x * 64;
    int t = threadIdx.x;
    if (t < C2_){ la[t] = a2c2[t]; lc[t] = a2c2[C2_ + t]; }
    __syncthreads();
    int ck = t & 15, ng = t >> 4;
    #pragma unroll
    for (int g = 0; g < 4; ++g){
        int n = g*16 + ng;
        uint4 v = *(const uint4*)(z2bf + ((size_t)b*N_ + n0 + n)*C2_ + ck*8);
        float f[8]; EXT8(f, v);
        #pragma unroll
        for (int e = 0; e < 8; ++e){
            int ch = ck*8 + e;
            T[ch][n] = fmaxf(fmaf(la[ch], f[e], lc[ch]), 0.f);
        }
    }
    __syncthreads();
    #pragma unroll
    for (int g = 0; g < 8; ++g){
        int id = g*256 + t;
        int ch = id >> 4, f4 = id & 15;
        float4 o;
        o.x = T[ch][f4*4+0]; o.y = T[ch][f4*4+1];
        o.z = T[ch][f4*4+2]; o.w = T[ch][f4*4+3];
        *(float4*)(out + ((size_t)b*C2_ + ch)*N_ + n0 + f4*4) = o;
    }
}

extern "C" void kernel_launch(void* const* d_in, const int* in_sizes, int n_in,
                              void* d_out, int out_size, void* d_ws, size_t ws_size,
                              hipStream_t stream){
    const float* xyz1    = (const float*)d_in[0];
    const float* xyz2    = (const float*)d_in[1];
    const float* points1 = (const float*)d_in[2];
    const float* points2 = (const float*)d_in[3];
    const float* w1      = (const float*)d_in[4];
    const float* gamma1  = (const float*)d_in[6];
    const float* beta1   = (const float*)d_in[7];
    const float* w2      = (const float*)d_in[8];
    const float* gamma2  = (const float*)d_in[10];
    const float* beta2   = (const float*)d_in[11];
    float* outp = (float*)d_out;

    char* ws = (char*)d_ws;
    size_t off = 0;
    auto take = [&](size_t sz) -> void* {
        void* p = ws + off;
        off = (off + sz + 255) & ~(size_t)255;
        return p;
    };
    int4*   nn_idx4 = (int4*)  take((size_t)B_*N_*16);
    float4* nn_w4   = (float4*)take((size_t)B_*N_*16);
    u16*    w1bf    = (u16*)   take((size_t)C1_*CIN_*2);
    u16*    w2bf    = (u16*)   take((size_t)C2_*C1_*2);
    u16*    p2t     = (u16*)   take((size_t)B_*S_*D2_*2);
    u16*    y1      = (u16*)   take((size_t)B_*N_*C1_*2);
    u16*    z2bf    = (u16*)   take((size_t)B_*N_*C2_*2);
    float*  part1   = (float*) take((size_t)2*512*C1_*4);
    float*  part2   = (float*) take((size_t)2*256*C2_*4);
    float*  a1c1    = (float*) take((size_t)2*C1_*4);
    float*  a2c2    = (float*) take((size_t)2*C2_*4);

    hipLaunchKernelGGL(k_pre, dim3(1024 + 4096 + 384), dim3(256), 0, stream,
                       xyz1, xyz2, points2, w1, w2, nn_idx4, nn_w4, p2t, w1bf, w2bf);
    hipLaunchKernelGGL(k_conv1, dim3(N_/128, B_), dim3(512), 0, stream,
                       w1bf, points1, p2t, nn_idx4, nn_w4, y1, part1);
    hipLaunchKernelGGL(k_finalize, dim3(C1_), dim3(256), 0, stream,
                       part1, C1_, 512, (float)(B_*N_), gamma1, beta1, a1c1);
    hipLaunchKernelGGL(k_conv2, dim3(N_/256, B_), dim3(512), 0, stream,
                       w2bf, y1, a1c1, z2bf, part2);
    hipLaunchKernelGGL(k_finalize, dim3(C2_), dim3(256), 0, stream,
                       part2, C2_, 256, (float)(B_*N_), gamma2, beta2, a2c2);
    hipLaunchKernelGGL(k_apply, dim3(N_/64, B_), dim3(256), 0, stream, z2bf, a2c2, outp);
    (void)in_sizes; (void)n_in; (void)out_size; (void)ws_size; (void)d_in;
}